// Round 2
// baseline (841.647 us; speedup 1.0000x reference)
//
#include <hip/hip_runtime.h>
#include <stdint.h>

typedef float f32x4 __attribute__((ext_vector_type(4)));
typedef __bf16 bf16x8 __attribute__((ext_vector_type(8)));

__device__ __forceinline__ uint16_t f2bf(float f) {
    uint32_t x = __builtin_bit_cast(uint32_t, f);
    uint32_t lsb = (x >> 16) & 1u;
    return (uint16_t)((x + 0x7fffu + lsb) >> 16);
}
__device__ __forceinline__ float bf2f(uint32_t u) {
    return __builtin_bit_cast(float, u << 16);
}

// Stage 16 contiguous K-elements into LDS, converting fp32 -> bf16 if needed.
__device__ __forceinline__ void stage16(const float* __restrict__ src, uint16_t* __restrict__ dst) {
    const float4* s4 = (const float4*)src;
    uint32_t pk[8];
#pragma unroll
    for (int c = 0; c < 4; ++c) {
        float4 f = s4[c];
        pk[2*c]   = (uint32_t)f2bf(f.x) | ((uint32_t)f2bf(f.y) << 16);
        pk[2*c+1] = (uint32_t)f2bf(f.z) | ((uint32_t)f2bf(f.w) << 16);
    }
    ((uint4*)dst)[0] = make_uint4(pk[0], pk[1], pk[2], pk[3]);
    ((uint4*)dst)[1] = make_uint4(pk[4], pk[5], pk[6], pk[7]);
}
__device__ __forceinline__ void stage16(const uint16_t* __restrict__ src, uint16_t* __restrict__ dst) {
    const uint4* s4 = (const uint4*)src;
    uint4 a = s4[0], b = s4[1];
    ((uint4*)dst)[0] = a;
    ((uint4*)dst)[1] = b;
}

// D[m][n] = (sum_k A[m][k] * B[n][k] + bias) * scale   (B given row-major [N][K], i.e. A·B^T)
// BIAS_MODE: 0 = none, 1 = bias[col], 2 = bias[row]
// TO: uint16_t (bf16 out) or float (fp32 out)
template<typename TA, typename TB, typename TO, int BIAS_MODE>
__global__ __launch_bounds__(256, 2) void gemm_bt(
    const TA* __restrict__ A, const TB* __restrict__ Bm,
    const float* __restrict__ bias, TO* __restrict__ D,
    int lda, int ldb, int ldd, int K, int ntn,
    long long sA, long long sB, long long sD, float scale)
{
    __shared__ uint16_t Ash[128 * 40];   // 128 rows x 32 k, padded to 40 (80B stride, <=2-way bank alias: free)
    __shared__ uint16_t Bsh[128 * 40];

    const int tm = blockIdx.x / ntn;
    const int tn = blockIdx.x % ntn;
    const int bz = blockIdx.y;
    A  += (size_t)bz * sA;
    Bm += (size_t)bz * sB;
    D  += (size_t)bz * sD;

    const int m0 = tm * 128, n0 = tn * 128;
    const int t = threadIdx.x;
    const int row = t >> 1, half = t & 1;           // staging: 2 threads/row, 16 elems each
    const int wid = t >> 6, lane = t & 63;
    const int wm = wid >> 1, wn = wid & 1;          // 2x2 waves, 64x64 per wave
    const int r16 = lane & 15, g = lane >> 4;       // fragment lane decomposition

    f32x4 acc[4][4];
#pragma unroll
    for (int i = 0; i < 4; ++i)
#pragma unroll
        for (int j = 0; j < 4; ++j)
            acc[i][j] = (f32x4){0.f, 0.f, 0.f, 0.f};

    const TA* aSrc = A  + (size_t)(m0 + row) * lda + half * 16;
    const TB* bSrc = Bm + (size_t)(n0 + row) * ldb + half * 16;
    uint16_t* aDst = &Ash[row * 40 + half * 16];
    uint16_t* bDst = &Bsh[row * 40 + half * 16];

    for (int k0 = 0; k0 < K; k0 += 32) {
        __syncthreads();
        stage16(aSrc + k0, aDst);
        stage16(bSrc + k0, bDst);
        __syncthreads();

        uint4 af[4], bf[4];
#pragma unroll
        for (int i = 0; i < 4; ++i)
            af[i] = *(const uint4*)&Ash[(wm * 64 + i * 16 + r16) * 40 + g * 8];
#pragma unroll
        for (int j = 0; j < 4; ++j)
            bf[j] = *(const uint4*)&Bsh[(wn * 64 + j * 16 + r16) * 40 + g * 8];

#pragma unroll
        for (int i = 0; i < 4; ++i)
#pragma unroll
            for (int j = 0; j < 4; ++j)
                acc[i][j] = __builtin_amdgcn_mfma_f32_16x16x32_bf16(
                    __builtin_bit_cast(bf16x8, af[i]),
                    __builtin_bit_cast(bf16x8, bf[j]),
                    acc[i][j], 0, 0, 0);
    }

#pragma unroll
    for (int i = 0; i < 4; ++i) {
        const int grow0 = m0 + wm * 64 + i * 16 + g * 4;
#pragma unroll
        for (int j = 0; j < 4; ++j) {
            const int gcol = n0 + wn * 64 + j * 16 + r16;
            float bcol = (BIAS_MODE == 1) ? bias[gcol] : 0.f;
#pragma unroll
            for (int r = 0; r < 4; ++r) {
                float v = acc[i][j][r];
                float bb = (BIAS_MODE == 1) ? bcol : ((BIAS_MODE == 2) ? bias[grow0 + r] : 0.f);
                v = (v + bb) * scale;
                if constexpr (sizeof(TO) == 2)
                    ((uint16_t*)D)[(size_t)(grow0 + r) * ldd + gcol] = f2bf(v);
                else
                    ((float*)D)[(size_t)(grow0 + r) * ldd + gcol] = v;
            }
        }
    }
}

// In-place row softmax over 2048 bf16 columns. One block (256 thr) per row.
__global__ __launch_bounds__(256) void softmax_rows(uint16_t* __restrict__ S)
{
    uint16_t* p = S + (size_t)blockIdx.x * 2048;
    const int t = threadIdx.x;
    const int wid = t >> 6, lane = t & 63;

    uint4 raw = ((const uint4*)p)[t];
    uint32_t w[4] = {raw.x, raw.y, raw.z, raw.w};
    float f[8];
#pragma unroll
    for (int c = 0; c < 4; ++c) {
        f[2*c]   = bf2f(w[c] & 0xffffu);
        f[2*c+1] = bf2f(w[c] >> 16);
    }

    float m = f[0];
#pragma unroll
    for (int j = 1; j < 8; ++j) m = fmaxf(m, f[j]);
#pragma unroll
    for (int off = 32; off; off >>= 1) m = fmaxf(m, __shfl_xor(m, off));

    __shared__ float redm[4], reds[4];
    if (lane == 0) redm[wid] = m;
    __syncthreads();
    m = fmaxf(fmaxf(redm[0], redm[1]), fmaxf(redm[2], redm[3]));

    float e[8], s = 0.f;
#pragma unroll
    for (int j = 0; j < 8; ++j) { e[j] = __expf(f[j] - m); s += e[j]; }
#pragma unroll
    for (int off = 32; off; off >>= 1) s += __shfl_xor(s, off);
    if (lane == 0) reds[wid] = s;
    __syncthreads();
    s = reds[0] + reds[1] + reds[2] + reds[3];
    float inv = 1.f / s;

    uint32_t o[4];
#pragma unroll
    for (int c = 0; c < 4; ++c)
        o[c] = (uint32_t)f2bf(e[2*c] * inv) | ((uint32_t)f2bf(e[2*c+1] * inv) << 16);
    ((uint4*)p)[t] = make_uint4(o[0], o[1], o[2], o[3]);
}

extern "C" void kernel_launch(void* const* d_in, const int* in_sizes, int n_in,
                              void* d_out, int out_size, void* d_ws, size_t ws_size,
                              hipStream_t stream)
{
    const float* q_in = (const float*)d_in[0];
    const float* k_in = (const float*)d_in[1];
    const float* v_in = (const float*)d_in[2];
    const float* Wq   = (const float*)d_in[3];
    const float* bq   = (const float*)d_in[4];
    const float* Wk   = (const float*)d_in[5];
    const float* bk   = (const float*)d_in[6];
    const float* Wv   = (const float*)d_in[7];
    const float* bv   = (const float*)d_in[8];

    const size_t MS = (size_t)16384 * 1024;      // 8*2048 x 1024
    const size_t SS = (size_t)8 * 2048 * 2048;   // scores
    size_t needed = (3 * MS + SS) * sizeof(uint16_t);
    if (ws_size < needed) return;  // fail loudly (validation mismatch) rather than corrupt

    uint16_t* Qb = (uint16_t*)d_ws;      // [16384][1024] bf16, pre-scaled 1/32
    uint16_t* Kb = Qb + MS;              // [16384][1024]
    uint16_t* VT = Kb + MS;              // [8][1024][2048]  (V transposed, per batch)
    uint16_t* Sc = VT + MS;              // [8][2048][2048]  scores -> P in place

    dim3 blk(256);

    // Q = (X Wq^T + bq) / 32 : M=16384 N=1024 K=1024
    gemm_bt<float, float, uint16_t, 1><<<dim3(128 * 8, 1), blk, 0, stream>>>(
        q_in, Wq, bq, Qb, 1024, 1024, 1024, 1024, 8, 0, 0, 0, 0.03125f);
    // K = X Wk^T + bk
    gemm_bt<float, float, uint16_t, 1><<<dim3(128 * 8, 1), blk, 0, stream>>>(
        k_in, Wk, bk, Kb, 1024, 1024, 1024, 1024, 8, 0, 0, 0, 1.0f);
    // V^T[b][f][s] = Wv[f][e] X[b][s][e] + bv[f] : M=1024 N=2048 K=1024, batched over B
    gemm_bt<float, float, uint16_t, 2><<<dim3(8 * 16, 8), blk, 0, stream>>>(
        Wv, v_in, bv, VT, 1024, 1024, 2048, 1024, 16,
        0, (long long)2048 * 1024, (long long)1024 * 2048, 1.0f);
    // S[b][q][k] = Q[b][q][:] . K[b][k][:]  (scale already folded into Q)
    gemm_bt<uint16_t, uint16_t, uint16_t, 0><<<dim3(16 * 16, 8), blk, 0, stream>>>(
        Qb, Kb, nullptr, Sc, 1024, 1024, 2048, 1024, 16,
        (long long)2048 * 1024, (long long)2048 * 1024, (long long)2048 * 2048, 1.0f);
    // P = softmax(S) rows, in place
    softmax_rows<<<dim3(8 * 2048), blk, 0, stream>>>(Sc);
    // out[b][q][e] = P[b][q][:] . VT[b][e][:]  : M=2048 N=1024 K=2048, fp32 out
    gemm_bt<uint16_t, uint16_t, float, 0><<<dim3(16 * 8, 8), blk, 0, stream>>>(
        Sc, VT, nullptr, (float*)d_out, 2048, 2048, 1024, 2048, 8,
        (long long)2048 * 2048, (long long)1024 * 2048, (long long)2048 * 1024, 1.0f);
}

// Round 3
// 591.197 us; speedup vs baseline: 1.4236x; 1.4236x over previous
//
#include <hip/hip_runtime.h>
#include <stdint.h>

typedef float f32x4 __attribute__((ext_vector_type(4)));
typedef __bf16 bf16x8 __attribute__((ext_vector_type(8)));

__device__ __forceinline__ uint16_t f2bf(float f) {
    uint32_t x = __builtin_bit_cast(uint32_t, f);
    uint32_t lsb = (x >> 16) & 1u;
    return (uint16_t)((x + 0x7fffu + lsb) >> 16);
}
__device__ __forceinline__ float bf2f(uint32_t u) {
    return __builtin_bit_cast(float, u << 16);
}

// async global->LDS, 16 bytes per lane. LDS dest is wave-uniform base + lane*16.
__device__ __forceinline__ void gload16(const uint16_t* g, uint16_t* l) {
    __builtin_amdgcn_global_load_lds(
        (const __attribute__((address_space(1))) uint32_t*)g,
        (__attribute__((address_space(3))) uint32_t*)l,
        16, 0, 0);
}

// fp32 -> bf16 (RNE), 8 elements/thread/iter, vectorized 32B read / 16B write.
__global__ __launch_bounds__(256) void cvt_f32_bf16(
    const float* __restrict__ src, uint16_t* __restrict__ dst, int n8)
{
    int idx = blockIdx.x * 256 + threadIdx.x;
    int stride = gridDim.x * 256;
    for (int i = idx; i < n8; i += stride) {
        const float4* s = (const float4*)src + 2 * (size_t)i;
        float4 a = s[0], b = s[1];
        uint4 o;
        o.x = (uint32_t)f2bf(a.x) | ((uint32_t)f2bf(a.y) << 16);
        o.y = (uint32_t)f2bf(a.z) | ((uint32_t)f2bf(a.w) << 16);
        o.z = (uint32_t)f2bf(b.x) | ((uint32_t)f2bf(b.y) << 16);
        o.w = (uint32_t)f2bf(b.z) | ((uint32_t)f2bf(b.w) << 16);
        ((uint4*)dst)[i] = o;
    }
}

// D[m][n] = (sum_k A[m][k]*B[n][k] + bias) * scale, all-bf16 inputs, m97 structure:
// 128x128 tile, BK=32, linear LDS [128][32], global_load_lds width-16 staging.
// BIAS_MODE: 0 none, 1 bias[col], 2 bias[row]. TO: uint16_t (bf16) or float.
template<typename TO, int BIAS_MODE>
__global__ __launch_bounds__(256, 2) void gemm_bf16(
    const uint16_t* __restrict__ A, const uint16_t* __restrict__ Bm,
    const float* __restrict__ bias, TO* __restrict__ D,
    int lda, int ldb, int ldd, int K, int ntn,
    long long sA, long long sB, long long sD, float scale)
{
    __shared__ uint16_t Ash[128 * 32];   // linear: row stride 64B (required by gload_lds)
    __shared__ uint16_t Bsh[128 * 32];

    const int tm = blockIdx.x / ntn;
    const int tn = blockIdx.x % ntn;
    const int bz = blockIdx.y;
    A  += (size_t)bz * sA;
    Bm += (size_t)bz * sB;
    D  += (size_t)bz * sD;

    const int m0 = tm * 128, n0 = tn * 128;
    const int t = threadIdx.x;
    const int wid = t >> 6, lane = t & 63;
    const int wm = wid >> 1, wn = wid & 1;          // 2x2 waves, 64x64 per wave
    const int r16 = lane & 15, g = lane >> 4;       // fragment lane decomposition

    // staging decomposition: chunk = 1KB = 16 rows x 64B; lane l covers
    // row = 16c + l/4, col-bytes = (l&3)*16. Wave w owns chunks 2w, 2w+1.
    const int lr = lane >> 2, l4 = lane & 3;
    const int c0 = 2 * wid;
    const int arow0 = c0 * 16 + lr;                 // rows arow0, arow0+16
    const int acol  = l4 * 8;                       // elements

    f32x4 acc[4][4];
#pragma unroll
    for (int i = 0; i < 4; ++i)
#pragma unroll
        for (int j = 0; j < 4; ++j)
            acc[i][j] = (f32x4){0.f, 0.f, 0.f, 0.f};

    const uint16_t* aS = A  + (size_t)(m0 + arow0) * lda + acol;
    const uint16_t* bS = Bm + (size_t)(n0 + arow0) * ldb + acol;
    uint16_t* aD0 = &Ash[c0 * 512];
    uint16_t* aD1 = &Ash[c0 * 512 + 512];
    uint16_t* bD0 = &Bsh[c0 * 512];
    uint16_t* bD1 = &Bsh[c0 * 512 + 512];

    for (int k0 = 0; k0 < K; k0 += 32) {
        __syncthreads();                 // previous tile fully consumed
        gload16(aS + k0, aD0);
        gload16(aS + k0 + (size_t)16 * lda, aD1);
        gload16(bS + k0, bD0);
        gload16(bS + k0 + (size_t)16 * ldb, bD1);
        __syncthreads();                 // compiler drains vmcnt before barrier

        uint4 af[4], bf[4];
#pragma unroll
        for (int i = 0; i < 4; ++i)
            af[i] = *(const uint4*)&Ash[(wm * 64 + i * 16 + r16) * 32 + g * 8];
#pragma unroll
        for (int j = 0; j < 4; ++j)
            bf[j] = *(const uint4*)&Bsh[(wn * 64 + j * 16 + r16) * 32 + g * 8];

#pragma unroll
        for (int i = 0; i < 4; ++i)
#pragma unroll
            for (int j = 0; j < 4; ++j)
                acc[i][j] = __builtin_amdgcn_mfma_f32_16x16x32_bf16(
                    __builtin_bit_cast(bf16x8, af[i]),
                    __builtin_bit_cast(bf16x8, bf[j]),
                    acc[i][j], 0, 0, 0);
    }

#pragma unroll
    for (int i = 0; i < 4; ++i) {
        const int grow0 = m0 + wm * 64 + i * 16 + g * 4;
#pragma unroll
        for (int j = 0; j < 4; ++j) {
            const int gcol = n0 + wn * 64 + j * 16 + r16;
            float bcol = (BIAS_MODE == 1) ? bias[gcol] : 0.f;
#pragma unroll
            for (int r = 0; r < 4; ++r) {
                float v = acc[i][j][r];
                float bb = (BIAS_MODE == 1) ? bcol : ((BIAS_MODE == 2) ? bias[grow0 + r] : 0.f);
                v = (v + bb) * scale;
                if constexpr (sizeof(TO) == 2)
                    ((uint16_t*)D)[(size_t)(grow0 + r) * ldd + gcol] = f2bf(v);
                else
                    ((float*)D)[(size_t)(grow0 + r) * ldd + gcol] = v;
            }
        }
    }
}

// In-place row softmax over 2048 bf16 columns. One block (256 thr) per row.
__global__ __launch_bounds__(256) void softmax_rows(uint16_t* __restrict__ S)
{
    uint16_t* p = S + (size_t)blockIdx.x * 2048;
    const int t = threadIdx.x;
    const int wid = t >> 6, lane = t & 63;

    uint4 raw = ((const uint4*)p)[t];
    uint32_t w[4] = {raw.x, raw.y, raw.z, raw.w};
    float f[8];
#pragma unroll
    for (int c = 0; c < 4; ++c) {
        f[2*c]   = bf2f(w[c] & 0xffffu);
        f[2*c+1] = bf2f(w[c] >> 16);
    }

    float m = f[0];
#pragma unroll
    for (int j = 1; j < 8; ++j) m = fmaxf(m, f[j]);
#pragma unroll
    for (int off = 32; off; off >>= 1) m = fmaxf(m, __shfl_xor(m, off));

    __shared__ float redm[4], reds[4];
    if (lane == 0) redm[wid] = m;
    __syncthreads();
    m = fmaxf(fmaxf(redm[0], redm[1]), fmaxf(redm[2], redm[3]));

    float e[8], s = 0.f;
#pragma unroll
    for (int j = 0; j < 8; ++j) { e[j] = __expf(f[j] - m); s += e[j]; }
#pragma unroll
    for (int off = 32; off; off >>= 1) s += __shfl_xor(s, off);
    if (lane == 0) reds[wid] = s;
    __syncthreads();
    s = reds[0] + reds[1] + reds[2] + reds[3];
    float inv = 1.f / s;

    uint32_t o[4];
#pragma unroll
    for (int c = 0; c < 4; ++c)
        o[c] = (uint32_t)f2bf(e[2*c] * inv) | ((uint32_t)f2bf(e[2*c+1] * inv) << 16);
    ((uint4*)p)[t] = make_uint4(o[0], o[1], o[2], o[3]);
}

extern "C" void kernel_launch(void* const* d_in, const int* in_sizes, int n_in,
                              void* d_out, int out_size, void* d_ws, size_t ws_size,
                              hipStream_t stream)
{
    const float* q_in = (const float*)d_in[0];
    const float* k_in = (const float*)d_in[1];
    const float* v_in = (const float*)d_in[2];
    const float* Wq   = (const float*)d_in[3];
    const float* bq   = (const float*)d_in[4];
    const float* Wk   = (const float*)d_in[5];
    const float* bk   = (const float*)d_in[6];
    const float* Wv   = (const float*)d_in[7];
    const float* bv   = (const float*)d_in[8];

    const size_t MS = (size_t)16384 * 1024;      // 16M elems (32 MB bf16)
    const size_t WS = (size_t)1024 * 1024;       // weight elems
    const size_t SS = (size_t)8 * 2048 * 2048;   // scores elems
    size_t needed = (3 * MS + SS) * sizeof(uint16_t);   // 160 MB
    if (ws_size < needed) return;

    uint16_t* Qb = (uint16_t*)d_ws;      // [16384][1024] bf16, pre-scaled 1/32
    uint16_t* Kb = Qb + MS;              // [16384][1024]
    uint16_t* VT = Kb + MS;              // [8][1024][2048] (V^T per batch)
    uint16_t* Sc = VT + MS;              // [8][2048][2048] scores -> P in place

    // temporaries that die before their region is written:
    uint16_t* Xv  = Sc;                  // 16M elems, dead after V-proj (scores writes later)
    uint16_t* Wqb = Sc + MS;             // 1M
    uint16_t* Wkb = Wqb + WS;
    uint16_t* Wvb = Wkb + WS;
    uint16_t* Xq  = (uint16_t*)d_out;    // d_out 64MB holds Xq+Xk bf16; PV overwrites at end
    uint16_t* Xk  = Xq + MS;

    dim3 blk(256);

    // fp32 -> bf16 converts
    cvt_f32_bf16<<<dim3(2048), blk, 0, stream>>>(q_in, Xq, (int)(MS / 8));
    cvt_f32_bf16<<<dim3(2048), blk, 0, stream>>>(k_in, Xk, (int)(MS / 8));
    cvt_f32_bf16<<<dim3(2048), blk, 0, stream>>>(v_in, Xv, (int)(MS / 8));
    cvt_f32_bf16<<<dim3(256),  blk, 0, stream>>>(Wq, Wqb, (int)(WS / 8));
    cvt_f32_bf16<<<dim3(256),  blk, 0, stream>>>(Wk, Wkb, (int)(WS / 8));
    cvt_f32_bf16<<<dim3(256),  blk, 0, stream>>>(Wv, Wvb, (int)(WS / 8));

    // Q = (Xq Wq^T + bq)/32 : M=16384 N=1024 K=1024
    gemm_bf16<uint16_t, 1><<<dim3(128 * 8, 1), blk, 0, stream>>>(
        Xq, Wqb, bq, Qb, 1024, 1024, 1024, 1024, 8, 0, 0, 0, 0.03125f);
    // K = Xk Wk^T + bk
    gemm_bf16<uint16_t, 1><<<dim3(128 * 8, 1), blk, 0, stream>>>(
        Xk, Wkb, bk, Kb, 1024, 1024, 1024, 1024, 8, 0, 0, 0, 1.0f);
    // V^T[b][f][s] = Wv[f][:] . Xv[b][s][:] + bv[f] : M=1024 N=2048 K=1024, batched
    gemm_bf16<uint16_t, 2><<<dim3(8 * 16, 8), blk, 0, stream>>>(
        Wvb, Xv, bv, VT, 1024, 1024, 2048, 1024, 16,
        0, (long long)2048 * 1024, (long long)1024 * 2048, 1.0f);
    // S[b][q][k] = Qb[b][q][:] . Kb[b][k][:] (1/sqrt(d) already in Qb)
    gemm_bf16<uint16_t, 0><<<dim3(16 * 16, 8), blk, 0, stream>>>(
        Qb, Kb, nullptr, Sc, 1024, 1024, 2048, 1024, 16,
        (long long)2048 * 1024, (long long)2048 * 1024, (long long)2048 * 2048, 1.0f);
    // P = softmax(S) rows, in place
    softmax_rows<<<dim3(8 * 2048), blk, 0, stream>>>(Sc);
    // out[b][q][e] = P[b][q][:] . VT[b][e][:] : M=2048 N=1024 K=2048, fp32 out
    gemm_bf16<float, 0><<<dim3(16 * 8, 8), blk, 0, stream>>>(
        Sc, VT, nullptr, (float*)d_out, 2048, 2048, 1024, 2048, 8,
        (long long)2048 * 2048, (long long)1024 * 2048, (long long)2048 * 1024, 1.0f);
}

// Round 4
// 575.953 us; speedup vs baseline: 1.4613x; 1.0265x over previous
//
#include <hip/hip_runtime.h>
#include <stdint.h>

typedef float f32x4 __attribute__((ext_vector_type(4)));
typedef __bf16 bf16x8 __attribute__((ext_vector_type(8)));

__device__ __forceinline__ uint16_t f2bf(float f) {
    uint32_t x = __builtin_bit_cast(uint32_t, f);
    uint32_t lsb = (x >> 16) & 1u;
    return (uint16_t)((x + 0x7fffu + lsb) >> 16);
}
__device__ __forceinline__ float bf2f(uint32_t u) {
    return __builtin_bit_cast(float, u << 16);
}

// async global->LDS, 16 bytes per lane. LDS dest is wave-uniform base + lane*16.
__device__ __forceinline__ void gload16(const uint16_t* g, uint16_t* l) {
    __builtin_amdgcn_global_load_lds(
        (const __attribute__((address_space(1))) uint32_t*)g,
        (__attribute__((address_space(3))) uint32_t*)l,
        16, 0, 0);
}

__global__ __launch_bounds__(256) void zero_f32(float* __restrict__ p, int n) {
    int i = blockIdx.x * 256 + threadIdx.x;
    if (i < n) p[i] = 0.f;
}

// fp32 -> bf16 (RNE), 8 elements/thread/iter, vectorized 32B read / 16B write.
__global__ __launch_bounds__(256) void cvt_f32_bf16(
    const float* __restrict__ src, uint16_t* __restrict__ dst, int n8)
{
    int idx = blockIdx.x * 256 + threadIdx.x;
    int stride = gridDim.x * 256;
    for (int i = idx; i < n8; i += stride) {
        const float4* s = (const float4*)src + 2 * (size_t)i;
        float4 a = s[0], b = s[1];
        uint4 o;
        o.x = (uint32_t)f2bf(a.x) | ((uint32_t)f2bf(a.y) << 16);
        o.y = (uint32_t)f2bf(a.z) | ((uint32_t)f2bf(a.w) << 16);
        o.z = (uint32_t)f2bf(b.x) | ((uint32_t)f2bf(b.y) << 16);
        o.w = (uint32_t)f2bf(b.z) | ((uint32_t)f2bf(b.w) << 16);
        ((uint4*)dst)[i] = o;
    }
}

// D = op(A.B^T), all-bf16 inputs, m97 structure: 128x128 tile, BK=32, linear LDS,
// global_load_lds width-16 staging, XCD-aware block swizzle (grid.x % 8 == 0).
// BIAS_MODE: 0 none, 1 bias[col], 2 bias[row].
// EPI: 0 = store (v+bias)*scale (bf16 or f32 per TO)
//      1 = store exp(v) bf16, atomicAdd row-sums of rounded exp into lsum[bz*2048+row]
//      2 = store v * (1/lsum[bz*2048+row]) as f32
template<typename TO, int BIAS_MODE, int EPI>
__global__ __launch_bounds__(256, 4) void gemm_bf16(
    const uint16_t* __restrict__ A, const uint16_t* __restrict__ Bm,
    const float* __restrict__ bias, float* __restrict__ lsum, TO* __restrict__ D,
    int lda, int ldb, int ldd, int K, int ntn,
    long long sA, long long sB, long long sD, float scale)
{
    __shared__ uint16_t Ash[128 * 32];   // linear: row stride 64B (required by gload_lds)
    __shared__ uint16_t Bsh[128 * 32];

    // XCD swizzle: contiguous chunk of blocks per XCD (bijective, nx % 8 == 0)
    int bid = blockIdx.x;
    const int nx = gridDim.x;
    bid = (bid & 7) * (nx >> 3) + (bid >> 3);
    const int tm = bid / ntn;
    const int tn = bid % ntn;
    const int bz = blockIdx.y;
    A  += (size_t)bz * sA;
    Bm += (size_t)bz * sB;
    D  += (size_t)bz * sD;
    float* lz = (EPI != 0) ? (lsum + (size_t)bz * 2048) : nullptr;

    const int m0 = tm * 128, n0 = tn * 128;
    const int t = threadIdx.x;
    const int wid = t >> 6, lane = t & 63;
    const int wm = wid >> 1, wn = wid & 1;          // 2x2 waves, 64x64 per wave
    const int r16 = lane & 15, g = lane >> 4;       // fragment lane decomposition

    // staging: chunk = 1KB = 16 rows x 64B; lane l covers row 16c + l/4, col-bytes (l&3)*16.
    const int lr = lane >> 2, l4 = lane & 3;
    const int c0 = 2 * wid;
    const int arow0 = c0 * 16 + lr;
    const int acol  = l4 * 8;

    f32x4 acc[4][4];
#pragma unroll
    for (int i = 0; i < 4; ++i)
#pragma unroll
        for (int j = 0; j < 4; ++j)
            acc[i][j] = (f32x4){0.f, 0.f, 0.f, 0.f};

    const uint16_t* aS = A  + (size_t)(m0 + arow0) * lda + acol;
    const uint16_t* bS = Bm + (size_t)(n0 + arow0) * ldb + acol;
    uint16_t* aD0 = &Ash[c0 * 512];
    uint16_t* aD1 = &Ash[c0 * 512 + 512];
    uint16_t* bD0 = &Bsh[c0 * 512];
    uint16_t* bD1 = &Bsh[c0 * 512 + 512];

    for (int k0 = 0; k0 < K; k0 += 32) {
        __syncthreads();
        gload16(aS + k0, aD0);
        gload16(aS + k0 + (size_t)16 * lda, aD1);
        gload16(bS + k0, bD0);
        gload16(bS + k0 + (size_t)16 * ldb, bD1);
        __syncthreads();

        uint4 af[4], bf[4];
#pragma unroll
        for (int i = 0; i < 4; ++i)
            af[i] = *(const uint4*)&Ash[(wm * 64 + i * 16 + r16) * 32 + g * 8];
#pragma unroll
        for (int j = 0; j < 4; ++j)
            bf[j] = *(const uint4*)&Bsh[(wn * 64 + j * 16 + r16) * 32 + g * 8];

#pragma unroll
        for (int i = 0; i < 4; ++i)
#pragma unroll
            for (int j = 0; j < 4; ++j)
                acc[i][j] = __builtin_amdgcn_mfma_f32_16x16x32_bf16(
                    __builtin_bit_cast(bf16x8, af[i]),
                    __builtin_bit_cast(bf16x8, bf[j]),
                    acc[i][j], 0, 0, 0);
    }

#pragma unroll
    for (int i = 0; i < 4; ++i) {
        const int grow0 = m0 + wm * 64 + i * 16 + g * 4;
        float rs[4] = {0.f, 0.f, 0.f, 0.f};
        float invl[4];
        if constexpr (EPI == 2) {
#pragma unroll
            for (int r = 0; r < 4; ++r) invl[r] = 1.0f / lz[grow0 + r];
        }
#pragma unroll
        for (int j = 0; j < 4; ++j) {
            const int gcol = n0 + wn * 64 + j * 16 + r16;
            float bcol = (BIAS_MODE == 1) ? bias[gcol] : 0.f;
#pragma unroll
            for (int r = 0; r < 4; ++r) {
                float v = acc[i][j][r];
                float bb = (BIAS_MODE == 1) ? bcol : ((BIAS_MODE == 2) ? bias[grow0 + r] : 0.f);
                v = (v + bb) * scale;
                if constexpr (EPI == 0) {
                    if constexpr (sizeof(TO) == 2)
                        ((uint16_t*)D)[(size_t)(grow0 + r) * ldd + gcol] = f2bf(v);
                    else
                        ((float*)D)[(size_t)(grow0 + r) * ldd + gcol] = v;
                } else if constexpr (EPI == 1) {
                    float e = __expf(v);
                    uint16_t h = f2bf(e);
                    ((uint16_t*)D)[(size_t)(grow0 + r) * ldd + gcol] = h;
                    rs[r] += bf2f(h);          // sum the ROUNDED value for consistency
                } else {
                    ((float*)D)[(size_t)(grow0 + r) * ldd + gcol] = v * invl[r];
                }
            }
        }
        if constexpr (EPI == 1) {
#pragma unroll
            for (int r = 0; r < 4; ++r) {
                float s = rs[r];
                s += __shfl_xor(s, 1);
                s += __shfl_xor(s, 2);
                s += __shfl_xor(s, 4);
                s += __shfl_xor(s, 8);
                if ((lane & 15) == 0) atomicAdd(&lz[grow0 + r], s);
            }
        }
    }
}

extern "C" void kernel_launch(void* const* d_in, const int* in_sizes, int n_in,
                              void* d_out, int out_size, void* d_ws, size_t ws_size,
                              hipStream_t stream)
{
    const float* q_in = (const float*)d_in[0];
    const float* k_in = (const float*)d_in[1];
    const float* v_in = (const float*)d_in[2];
    const float* Wq   = (const float*)d_in[3];
    const float* bq   = (const float*)d_in[4];
    const float* Wk   = (const float*)d_in[5];
    const float* bk   = (const float*)d_in[6];
    const float* Wv   = (const float*)d_in[7];
    const float* bv   = (const float*)d_in[8];

    const size_t MS = (size_t)16384 * 1024;      // 16M elems (32 MB bf16)
    const size_t WS = (size_t)1024 * 1024;       // weight elems
    const size_t SS = (size_t)8 * 2048 * 2048;   // scores elems
    size_t needed = (3 * MS + SS) * sizeof(uint16_t) + 16384 * sizeof(float);
    if (ws_size < needed) return;

    uint16_t* Qb = (uint16_t*)d_ws;      // [16384][1024] bf16, pre-scaled 1/32
    uint16_t* Kb = Qb + MS;              // [16384][1024]
    uint16_t* VT = Kb + MS;              // [8][1024][2048] (V^T per batch)
    uint16_t* Sc = VT + MS;              // [8][2048][2048] E = exp(scores)
    float*    lrow = (float*)(Sc + SS);  // [8][2048] row sums of E

    // temporaries that die before their region is written:
    uint16_t* Xv  = Sc;                  // dead after V-proj (scores written later)
    uint16_t* Wqb = Sc + MS;
    uint16_t* Wkb = Wqb + WS;
    uint16_t* Wvb = Wkb + WS;
    uint16_t* Xq  = (uint16_t*)d_out;    // d_out holds Xq+Xk bf16; PV overwrites at end
    uint16_t* Xk  = Xq + MS;

    dim3 blk(256);

    zero_f32<<<dim3(64), blk, 0, stream>>>(lrow, 16384);

    cvt_f32_bf16<<<dim3(2048), blk, 0, stream>>>(q_in, Xq, (int)(MS / 8));
    cvt_f32_bf16<<<dim3(2048), blk, 0, stream>>>(k_in, Xk, (int)(MS / 8));
    cvt_f32_bf16<<<dim3(2048), blk, 0, stream>>>(v_in, Xv, (int)(MS / 8));
    cvt_f32_bf16<<<dim3(256),  blk, 0, stream>>>(Wq, Wqb, (int)(WS / 8));
    cvt_f32_bf16<<<dim3(256),  blk, 0, stream>>>(Wk, Wkb, (int)(WS / 8));
    cvt_f32_bf16<<<dim3(256),  blk, 0, stream>>>(Wv, Wvb, (int)(WS / 8));

    // Q = (Xq Wq^T + bq)/32 : M=16384 N=1024 K=1024
    gemm_bf16<uint16_t, 1, 0><<<dim3(128 * 8, 1), blk, 0, stream>>>(
        Xq, Wqb, bq, nullptr, Qb, 1024, 1024, 1024, 1024, 8, 0, 0, 0, 0.03125f);
    // K = Xk Wk^T + bk
    gemm_bf16<uint16_t, 1, 0><<<dim3(128 * 8, 1), blk, 0, stream>>>(
        Xk, Wkb, bk, nullptr, Kb, 1024, 1024, 1024, 1024, 8, 0, 0, 0, 1.0f);
    // V^T[b][f][s] = Wv[f][:] . Xv[b][s][:] + bv[f] : M=1024 N=2048 K=1024, batched
    gemm_bf16<uint16_t, 2, 0><<<dim3(8 * 16, 8), blk, 0, stream>>>(
        Wvb, Xv, bv, nullptr, VT, 1024, 1024, 2048, 1024, 16,
        0, (long long)2048 * 1024, (long long)1024 * 2048, 1.0f);
    // E[b][q][k] = exp(Qb[b][q][:] . Kb[b][k][:]) ; lrow[b][q] += row sums
    gemm_bf16<uint16_t, 0, 1><<<dim3(16 * 16, 8), blk, 0, stream>>>(
        Qb, Kb, nullptr, lrow, Sc, 1024, 1024, 2048, 1024, 16,
        (long long)2048 * 1024, (long long)2048 * 1024, (long long)2048 * 2048, 1.0f);
    // out[b][q][e] = (E[b][q][:] . VT[b][e][:]) / lrow[b][q] : fp32 out
    gemm_bf16<float, 0, 2><<<dim3(16 * 8, 8), blk, 0, stream>>>(
        Sc, VT, nullptr, lrow, (float*)d_out, 2048, 2048, 1024, 2048, 8,
        (long long)2048 * 2048, (long long)1024 * 2048, (long long)2048 * 1024, 1.0f);
}

// Round 5
// 568.583 us; speedup vs baseline: 1.4803x; 1.0130x over previous
//
#include <hip/hip_runtime.h>
#include <stdint.h>

typedef float f32x4 __attribute__((ext_vector_type(4)));
typedef __bf16 bf16x8 __attribute__((ext_vector_type(8)));

__device__ __forceinline__ uint16_t f2bf(float f) {
    uint32_t x = __builtin_bit_cast(uint32_t, f);
    uint32_t lsb = (x >> 16) & 1u;
    return (uint16_t)((x + 0x7fffu + lsb) >> 16);
}
__device__ __forceinline__ float bf2f(uint32_t u) {
    return __builtin_bit_cast(float, u << 16);
}

// async global->LDS, 16B/lane; LDS dest = wave-uniform base + lane*16.
__device__ __forceinline__ void gload16(const uint16_t* g, const uint8_t* l) {
    __builtin_amdgcn_global_load_lds(
        (const __attribute__((address_space(1))) uint32_t*)g,
        (__attribute__((address_space(3))) uint32_t*)l,
        16, 0, 0);
}

__global__ __launch_bounds__(256) void zero_f32(float* __restrict__ p, int n) {
    int i = blockIdx.x * 256 + threadIdx.x;
    if (i < n) p[i] = 0.f;
}

// fp32->bf16 (RNE) for 3 equal-size arrays; blockIdx.y selects array.
__global__ __launch_bounds__(256) void cvt3_f32_bf16(
    const float* __restrict__ s0, const float* __restrict__ s1, const float* __restrict__ s2,
    uint16_t* __restrict__ d0, uint16_t* __restrict__ d1, uint16_t* __restrict__ d2, int n8)
{
    const float* src = (blockIdx.y == 0) ? s0 : (blockIdx.y == 1) ? s1 : s2;
    uint16_t*   dst = (blockIdx.y == 0) ? d0 : (blockIdx.y == 1) ? d1 : d2;
    int idx = blockIdx.x * 256 + threadIdx.x;
    int stride = gridDim.x * 256;
    for (int i = idx; i < n8; i += stride) {
        const float4* s = (const float4*)src + 2 * (size_t)i;
        float4 a = s[0], b = s[1];
        uint4 o;
        o.x = (uint32_t)f2bf(a.x) | ((uint32_t)f2bf(a.y) << 16);
        o.y = (uint32_t)f2bf(a.z) | ((uint32_t)f2bf(a.w) << 16);
        o.z = (uint32_t)f2bf(b.x) | ((uint32_t)f2bf(b.y) << 16);
        o.w = (uint32_t)f2bf(b.z) | ((uint32_t)f2bf(b.w) << 16);
        ((uint4*)dst)[i] = o;
    }
}

// ---------------------------------------------------------------------------
// 256x256 deep-pipelined bf16 GEMM: D = op(A.B^T).
// BK=32, 3-slot LDS rotation (96KB), 2 phases/K-tile, counted vmcnt(4) + one
// raw s_barrier per K-tile (loads stay in flight across barriers), setprio
// around MFMA clusters, XOR-swizzled LDS (pre-swizzled global source, 2-way
// residual conflict = free). 512 threads = 8 waves (2m x 4n), wave tile 128x64.
// BIAS_MODE: 0 none, 1 bias[col], 2 bias[row].
// EPI: 0 = store (v+bias)*scale ; 1 = store exp(v) bf16 + atomic rowsum into
//      lsum[bz*2048+row] ; 2 = store v * (1/lsum[bz*2048+row]) as f32.
// ---------------------------------------------------------------------------
template<typename TO, int BIAS_MODE, int EPI>
__global__ __launch_bounds__(512, 2) void gemm256(
    const uint16_t* __restrict__ A, const uint16_t* __restrict__ Bm,
    const float* __restrict__ bias, float* __restrict__ lsum, TO* __restrict__ D,
    int lda, int ldb, int ldd, int K, int ntn,
    long long sA, long long sB, long long sD, float scale)
{
    __shared__ uint4 ldsq[6144];               // 3 slots x (A 16KB + B 16KB)
    uint8_t* ldsb = (uint8_t*)ldsq;

    // XCD swizzle (bijective: nx % 8 == 0 for all our grids)
    int bid = blockIdx.x;
    const int nx = gridDim.x;
    bid = (bid & 7) * (nx >> 3) + (bid >> 3);
    const int tm = bid / ntn, tn = bid % ntn;
    const int bz = blockIdx.y;
    A  += (size_t)bz * sA;
    Bm += (size_t)bz * sB;
    D  += (size_t)bz * sD;
    float* lz = (EPI != 0) ? (lsum + (size_t)bz * 2048) : nullptr;

    const int m0 = tm * 256, n0 = tn * 256;
    const int t = threadIdx.x;
    const int wid = t >> 6, lane = t & 63;
    const int wm = wid >> 2, wn = wid & 3;      // 2 x 4 waves, 128x64 per wave
    const int r16 = lane & 15, g = lane >> 4;

    // swizzled per-lane ds_read offset: row r16 (64B stride), phys 16B-slot = g ^ ((r16>>1)&3)
    const int lco = r16 * 64 + ((g ^ ((r16 >> 1) & 3)) << 4);

    // staging: chunk c = 2*wid + i covers rows 16c..16c+15 (1KB linear LDS);
    // lane: row-in-chunk = lane>>2, phys slot = lane&3, logical slot pre-swizzled:
    const int sslot = (lane & 3) ^ ((lane >> 3) & 3);
    const int c0 = 2 * wid;
    const int gr0 = c0 * 16 + (lane >> 2);
    const uint16_t* aS0 = A  + (size_t)(m0 + gr0) * lda + sslot * 8;
    const uint16_t* aS1 = A  + (size_t)(m0 + gr0 + 16) * lda + sslot * 8;
    const uint16_t* bS0 = Bm + (size_t)(n0 + gr0) * ldb + sslot * 8;
    const uint16_t* bS1 = Bm + (size_t)(n0 + gr0 + 16) * ldb + sslot * 8;
    const int dA0 = c0 * 1024, dA1 = dA0 + 1024;

#define STAGE_A(sl, kk) do { uint8_t* _b = ldsb + (sl) * 32768; \
    gload16(aS0 + (kk), _b + dA0); gload16(aS1 + (kk), _b + dA1); } while (0)
#define STAGE_B(sl, kk) do { uint8_t* _b = ldsb + (sl) * 32768 + 16384; \
    gload16(bS0 + (kk), _b + dA0); gload16(bS1 + (kk), _b + dA1); } while (0)

    f32x4 acc[8][4];
#pragma unroll
    for (int i = 0; i < 8; ++i)
#pragma unroll
        for (int j = 0; j < 4; ++j)
            acc[i][j] = (f32x4){0.f, 0.f, 0.f, 0.f};

    const int NT = K >> 5;                      // K-tiles of 32
    // prologue: tiles 0 and 1 into slots 0 and 1 (8 loads/thread outstanding)
    STAGE_A(0, 0); STAGE_B(0, 0);
    STAGE_A(1, 32); STAGE_B(1, 32);

    int s_cur = 0;
    for (int tt = 0; tt < NT; ++tt) {
        int s2 = s_cur + 2; if (s2 >= 3) s2 -= 3;          // (tt+2)%3
        int t2 = tt + 2; if (t2 >= NT) t2 -= NT;           // wraparound tail restage (dead slot)
        const int kk2 = t2 << 5;

        // own tile-tt loads (issued at tt-2) retired; tile-(tt+1) loads stay in flight
        asm volatile("s_waitcnt vmcnt(4)" ::: "memory");
        __builtin_amdgcn_s_barrier();
        asm volatile("" ::: "memory");

        const uint8_t* Ab = ldsb + s_cur * 32768 + wm * 8192;
        const uint8_t* Bb = ldsb + s_cur * 32768 + 16384 + wn * 4096;

        // phase 0: issue A-stage for tt+2, read A frags + B half0, 16 MFMA
        STAGE_A(s2, kk2);
        uint4 af[8], bfr[4];
#pragma unroll
        for (int m = 0; m < 8; ++m)
            af[m] = *(const uint4*)(Ab + m * 1024 + lco);
        bfr[0] = *(const uint4*)(Bb + lco);
        bfr[1] = *(const uint4*)(Bb + 1024 + lco);
        __builtin_amdgcn_s_setprio(1);
#pragma unroll
        for (int m = 0; m < 8; ++m) {
            acc[m][0] = __builtin_amdgcn_mfma_f32_16x16x32_bf16(
                __builtin_bit_cast(bf16x8, af[m]), __builtin_bit_cast(bf16x8, bfr[0]), acc[m][0], 0, 0, 0);
            acc[m][1] = __builtin_amdgcn_mfma_f32_16x16x32_bf16(
                __builtin_bit_cast(bf16x8, af[m]), __builtin_bit_cast(bf16x8, bfr[1]), acc[m][1], 0, 0, 0);
        }
        __builtin_amdgcn_s_setprio(0);

        // phase 1: issue B-stage for tt+2, read B half1, 16 MFMA
        STAGE_B(s2, kk2);
        bfr[2] = *(const uint4*)(Bb + 2048 + lco);
        bfr[3] = *(const uint4*)(Bb + 3072 + lco);
        __builtin_amdgcn_s_setprio(1);
#pragma unroll
        for (int m = 0; m < 8; ++m) {
            acc[m][2] = __builtin_amdgcn_mfma_f32_16x16x32_bf16(
                __builtin_bit_cast(bf16x8, af[m]), __builtin_bit_cast(bf16x8, bfr[2]), acc[m][2], 0, 0, 0);
            acc[m][3] = __builtin_amdgcn_mfma_f32_16x16x32_bf16(
                __builtin_bit_cast(bf16x8, af[m]), __builtin_bit_cast(bf16x8, bfr[3]), acc[m][3], 0, 0, 0);
        }
        __builtin_amdgcn_s_setprio(0);

        s_cur += 1; if (s_cur >= 3) s_cur = 0;
    }
#undef STAGE_A
#undef STAGE_B

    // epilogue
#pragma unroll
    for (int mf = 0; mf < 8; ++mf) {
        const int grow0 = m0 + wm * 128 + mf * 16 + g * 4;
        float rs[4] = {0.f, 0.f, 0.f, 0.f};
        float invl[4];
        if constexpr (EPI == 2) {
#pragma unroll
            for (int r = 0; r < 4; ++r) invl[r] = 1.0f / lz[grow0 + r];
        }
#pragma unroll
        for (int nf = 0; nf < 4; ++nf) {
            const int gcol = n0 + wn * 64 + nf * 16 + r16;
            float bcol = (BIAS_MODE == 1) ? bias[gcol] : 0.f;
#pragma unroll
            for (int r = 0; r < 4; ++r) {
                float v = acc[mf][nf][r];
                float bb = (BIAS_MODE == 1) ? bcol : ((BIAS_MODE == 2) ? bias[grow0 + r] : 0.f);
                v = (v + bb) * scale;
                if constexpr (EPI == 0) {
                    if constexpr (sizeof(TO) == 2)
                        ((uint16_t*)D)[(size_t)(grow0 + r) * ldd + gcol] = f2bf(v);
                    else
                        ((float*)D)[(size_t)(grow0 + r) * ldd + gcol] = v;
                } else if constexpr (EPI == 1) {
                    float e = __expf(v);
                    uint16_t h = f2bf(e);
                    ((uint16_t*)D)[(size_t)(grow0 + r) * ldd + gcol] = h;
                    rs[r] += bf2f(h);          // sum the ROUNDED value for consistency
                } else {
                    ((float*)D)[(size_t)(grow0 + r) * ldd + gcol] = v * invl[r];
                }
            }
        }
        if constexpr (EPI == 1) {
#pragma unroll
            for (int r = 0; r < 4; ++r) {
                float s = rs[r];
                s += __shfl_xor(s, 1);
                s += __shfl_xor(s, 2);
                s += __shfl_xor(s, 4);
                s += __shfl_xor(s, 8);
                if ((lane & 15) == 0) atomicAdd(&lz[grow0 + r], s);
            }
        }
    }
}

extern "C" void kernel_launch(void* const* d_in, const int* in_sizes, int n_in,
                              void* d_out, int out_size, void* d_ws, size_t ws_size,
                              hipStream_t stream)
{
    const float* q_in = (const float*)d_in[0];
    const float* k_in = (const float*)d_in[1];
    const float* v_in = (const float*)d_in[2];
    const float* Wq   = (const float*)d_in[3];
    const float* bq   = (const float*)d_in[4];
    const float* Wk   = (const float*)d_in[5];
    const float* bk   = (const float*)d_in[6];
    const float* Wv   = (const float*)d_in[7];
    const float* bv   = (const float*)d_in[8];

    const size_t MS = (size_t)16384 * 1024;      // 16M elems (32 MB bf16)
    const size_t WS = (size_t)1024 * 1024;       // weight elems
    const size_t SS = (size_t)8 * 2048 * 2048;   // scores elems
    size_t needed = (3 * MS + SS) * sizeof(uint16_t) + 16384 * sizeof(float);
    if (ws_size < needed) return;

    uint16_t* Qb = (uint16_t*)d_ws;      // [16384][1024] bf16, pre-scaled 1/32
    uint16_t* Kb = Qb + MS;              // [16384][1024]
    uint16_t* VT = Kb + MS;              // [8][1024][2048] (V^T per batch)
    uint16_t* Sc = VT + MS;              // [8][2048][2048] E = exp(scores)
    float*    lrow = (float*)(Sc + SS);  // [8][2048] row sums of E

    // temporaries that die before their region is overwritten:
    uint16_t* Xv  = Sc;                  // dead after V-proj (scores written later)
    uint16_t* Wqb = Sc + MS;
    uint16_t* Wkb = Wqb + WS;
    uint16_t* Wvb = Wkb + WS;
    uint16_t* Xq  = (uint16_t*)d_out;    // d_out holds Xq+Xk bf16; PV overwrites at end
    uint16_t* Xk  = Xq + MS;

    dim3 blk(256);
    dim3 blk5(512);

    zero_f32<<<dim3(64), blk, 0, stream>>>(lrow, 16384);

    cvt3_f32_bf16<<<dim3(1024, 3), blk, 0, stream>>>(
        q_in, k_in, v_in, Xq, Xk, Xv, (int)(MS / 8));
    cvt3_f32_bf16<<<dim3(128, 3), blk, 0, stream>>>(
        Wq, Wk, Wv, Wqb, Wkb, Wvb, (int)(WS / 8));

    // Q = (Xq Wq^T + bq)/32 : M=16384 N=1024 K=1024 -> grid 64x4
    gemm256<uint16_t, 1, 0><<<dim3(256, 1), blk5, 0, stream>>>(
        Xq, Wqb, bq, nullptr, Qb, 1024, 1024, 1024, 1024, 4, 0, 0, 0, 0.03125f);
    // K = Xk Wk^T + bk
    gemm256<uint16_t, 1, 0><<<dim3(256, 1), blk5, 0, stream>>>(
        Xk, Wkb, bk, nullptr, Kb, 1024, 1024, 1024, 1024, 4, 0, 0, 0, 1.0f);
    // V^T[b][f][s] = Wv[f][:] . Xv[b][s][:] + bv[f] : M=1024 N=2048 K=1024 -> 4x8 per batch
    gemm256<uint16_t, 2, 0><<<dim3(32, 8), blk5, 0, stream>>>(
        Wvb, Xv, bv, nullptr, VT, 1024, 1024, 2048, 1024, 8,
        0, (long long)2048 * 1024, (long long)1024 * 2048, 1.0f);
    // E[b][q][k] = exp(Qb[b][q][:] . Kb[b][k][:]) ; lrow[b][q] += row sums
    gemm256<uint16_t, 0, 1><<<dim3(64, 8), blk5, 0, stream>>>(
        Qb, Kb, nullptr, lrow, Sc, 1024, 1024, 2048, 1024, 8,
        (long long)2048 * 1024, (long long)2048 * 1024, (long long)2048 * 2048, 1.0f);
    // out[b][q][e] = (E[b][q][:] . VT[b][e][:]) / lrow[b][q] : M=2048 N=1024 K=2048
    gemm256<float, 0, 2><<<dim3(32, 8), blk5, 0, stream>>>(
        Sc, VT, nullptr, lrow, (float*)d_out, 2048, 2048, 1024, 2048, 4,
        (long long)2048 * 2048, (long long)1024 * 2048, (long long)2048 * 1024, 1.0f);
}

// Round 6
// 523.441 us; speedup vs baseline: 1.6079x; 1.0862x over previous
//
#include <hip/hip_runtime.h>
#include <stdint.h>

typedef float f32x4 __attribute__((ext_vector_type(4)));
typedef __bf16 bf16x8 __attribute__((ext_vector_type(8)));

__device__ __forceinline__ uint16_t f2bf(float f) {
    uint32_t x = __builtin_bit_cast(uint32_t, f);
    uint32_t lsb = (x >> 16) & 1u;
    return (uint16_t)((x + 0x7fffu + lsb) >> 16);
}
__device__ __forceinline__ float bf2f(uint32_t u) {
    return __builtin_bit_cast(float, u << 16);
}

// async global->LDS, 16B/lane; LDS dest = wave-uniform base + lane*16.
__device__ __forceinline__ void gload16(const uint16_t* g, const uint8_t* l) {
    __builtin_amdgcn_global_load_lds(
        (const __attribute__((address_space(1))) uint32_t*)g,
        (__attribute__((address_space(3))) uint32_t*)l,
        16, 0, 0);
}

__global__ __launch_bounds__(256) void zero_f32(float* __restrict__ p, int n) {
    int i = blockIdx.x * 256 + threadIdx.x;
    if (i < n) p[i] = 0.f;
}

// fp32->bf16 (RNE) for 3 equal-size arrays; blockIdx.y selects array.
__global__ __launch_bounds__(256) void cvt3_f32_bf16(
    const float* __restrict__ s0, const float* __restrict__ s1, const float* __restrict__ s2,
    uint16_t* __restrict__ d0, uint16_t* __restrict__ d1, uint16_t* __restrict__ d2, int n8)
{
    const float* src = (blockIdx.y == 0) ? s0 : (blockIdx.y == 1) ? s1 : s2;
    uint16_t*   dst = (blockIdx.y == 0) ? d0 : (blockIdx.y == 1) ? d1 : d2;
    int idx = blockIdx.x * 256 + threadIdx.x;
    int stride = gridDim.x * 256;
    for (int i = idx; i < n8; i += stride) {
        const float4* s = (const float4*)src + 2 * (size_t)i;
        float4 a = s[0], b = s[1];
        uint4 o;
        o.x = (uint32_t)f2bf(a.x) | ((uint32_t)f2bf(a.y) << 16);
        o.y = (uint32_t)f2bf(a.z) | ((uint32_t)f2bf(a.w) << 16);
        o.z = (uint32_t)f2bf(b.x) | ((uint32_t)f2bf(b.y) << 16);
        o.w = (uint32_t)f2bf(b.z) | ((uint32_t)f2bf(b.w) << 16);
        ((uint4*)dst)[i] = o;
    }
}

#define SCHED0() __builtin_amdgcn_sched_barrier(0)

// ---------------------------------------------------------------------------
// 256x256 bf16 GEMM, m201-style phase discipline: BK=32, 4-slot LDS rotation
// (128KB), per K-tile 2 hard phases {reads; 2 gloads; barrier; setprio; 16
// MFMA; setprio; barrier}, one counted vmcnt(4) per K-tile (never 0 in-loop),
// zero-conflict XOR swizzle (pre-swizzled global source + swizzled ds_read).
// 512 thr = 8 waves (2m x 4n), wave tile 128x64.
// BIAS_MODE: 0 none, 1 bias[col], 2 bias[row].
// EPI: 0 store (v+bias)*scale ; 1 store exp(v) bf16 + atomic rowsum into
//      lsum[bz*2048+row] ; 2 store v * (1/lsum[bz*2048+row]) as f32.
// ---------------------------------------------------------------------------
template<typename TO, int BIAS_MODE, int EPI>
__global__ __launch_bounds__(512, 1) void gemm256(
    const uint16_t* __restrict__ A, const uint16_t* __restrict__ Bm,
    const float* __restrict__ bias, float* __restrict__ lsum, TO* __restrict__ D,
    int lda, int ldb, int ldd, int K, int ntn,
    long long sA, long long sB, long long sD, float scale)
{
    __shared__ uint4 ldsq[8192];               // 4 slots x (A 16KB + B 16KB) = 128KB
    uint8_t* ldsb = (uint8_t*)ldsq;

    // XCD swizzle (bijective: nx % 8 == 0 for all our grids)
    int bid = blockIdx.x;
    const int nx = gridDim.x;
    bid = (bid & 7) * (nx >> 3) + (bid >> 3);
    const int tm = bid / ntn, tn = bid % ntn;
    const int bz = blockIdx.y;
    A  += (size_t)bz * sA;
    Bm += (size_t)bz * sB;
    D  += (size_t)bz * sD;
    float* lz = (EPI != 0) ? (lsum + (size_t)bz * 2048) : nullptr;

    const int m0 = tm * 256, n0 = tn * 256;
    const int t = threadIdx.x;
    const int wid = t >> 6, lane = t & 63;
    const int wm = wid >> 2, wn = wid & 3;      // 2 x 4 waves, 128x64 per wave
    const int r16 = lane & 15, g = lane >> 4;

    // swizzled ds_read offset: row r16 (64B stride), phys 16B-slot = g ^ ((r16>>1)&3)
    const int lco = r16 * 64 + ((g ^ ((r16 >> 1) & 3)) << 4);

    // staging: wave w stages rows [16w..16w+15] (half0) and [128+16w..] (half1)
    // of the 256-row tile; lane covers row-in-chunk lane>>2, phys slot lane&3,
    // global 16B-slot pre-swizzled to match the read swizzle.
    const int sslot = (lane & 3) ^ ((lane >> 3) & 3);
    const int gr0 = wid * 16 + (lane >> 2);
    const uint16_t* aS0 = A  + (size_t)(m0 + gr0) * lda + sslot * 8;
    const uint16_t* aS1 = A  + (size_t)(m0 + gr0 + 128) * lda + sslot * 8;
    const uint16_t* bS0 = Bm + (size_t)(n0 + gr0) * ldb + sslot * 8;
    const uint16_t* bS1 = Bm + (size_t)(n0 + gr0 + 128) * ldb + sslot * 8;
    const int dA0 = wid * 1024, dA1 = 8192 + wid * 1024;

    f32x4 acc[8][4];
#pragma unroll
    for (int i = 0; i < 8; ++i)
#pragma unroll
        for (int j = 0; j < 4; ++j)
            acc[i][j] = (f32x4){0.f, 0.f, 0.f, 0.f};

    const int NT = K >> 5;                      // K-tiles of 32

    // prologue: tiles 0,1 -> slots 0,1 (per-tile grouped: 4 loads each)
    {
        uint8_t* b0 = ldsb;
        gload16(aS0, b0 + dA0); gload16(aS1, b0 + dA1);
        gload16(bS0, b0 + 16384 + dA0); gload16(bS1, b0 + 16384 + dA1);
        uint8_t* b1 = ldsb + 32768;
        gload16(aS0 + 32, b1 + dA0); gload16(aS1 + 32, b1 + dA1);
        gload16(bS0 + 32, b1 + 16384 + dA0); gload16(bS1 + 32, b1 + 16384 + dA1);
    }
    asm volatile("s_waitcnt vmcnt(4)" ::: "memory");   // tile 0 landed
    SCHED0();
    __builtin_amdgcn_s_barrier();
    SCHED0();

    int s_cur = 0;
    for (int tt = 0; tt < NT; ++tt) {
        int s2 = s_cur + 2; if (s2 >= 4) s2 -= 4;      // (tt+2)%4
        int t2 = tt + 2; if (t2 >= NT) t2 -= NT;       // wrap: restage dead slot
        const int kk2 = t2 << 5;

        const uint8_t* Ab = ldsb + s_cur * 32768 + wm * 8192;
        const uint8_t* Bb = ldsb + s_cur * 32768 + 16384 + wn * 4096;
        uint8_t* SA = ldsb + s2 * 32768;
        uint8_t* SB = SA + 16384;

        // ---------- phase A: read A0-7 + B0-1, stage A-halves, MFMA n0,n1 ----
        uint4 af[8], bfr[4];
#pragma unroll
        for (int m = 0; m < 8; ++m)
            af[m] = *(const uint4*)(Ab + m * 1024 + lco);
        bfr[0] = *(const uint4*)(Bb + lco);
        bfr[1] = *(const uint4*)(Bb + 1024 + lco);
        gload16(aS0 + kk2, SA + dA0);
        gload16(aS1 + kk2, SA + dA1);
        SCHED0();
        __builtin_amdgcn_s_barrier();
        SCHED0();
        __builtin_amdgcn_s_setprio(1);
#pragma unroll
        for (int m = 0; m < 8; ++m) {
            acc[m][0] = __builtin_amdgcn_mfma_f32_16x16x32_bf16(
                __builtin_bit_cast(bf16x8, af[m]), __builtin_bit_cast(bf16x8, bfr[0]), acc[m][0], 0, 0, 0);
            acc[m][1] = __builtin_amdgcn_mfma_f32_16x16x32_bf16(
                __builtin_bit_cast(bf16x8, af[m]), __builtin_bit_cast(bf16x8, bfr[1]), acc[m][1], 0, 0, 0);
        }
        __builtin_amdgcn_s_setprio(0);
        SCHED0();
        __builtin_amdgcn_s_barrier();
        SCHED0();

        // ---------- phase B: read B2-3, stage B-halves, vmcnt gate, MFMA n2,n3
        bfr[2] = *(const uint4*)(Bb + 2048 + lco);
        bfr[3] = *(const uint4*)(Bb + 3072 + lco);
        gload16(bS0 + kk2, SB + dA0);
        gload16(bS1 + kk2, SB + dA1);
        asm volatile("s_waitcnt vmcnt(4)" ::: "memory");   // tile tt+1 landed
        SCHED0();
        __builtin_amdgcn_s_barrier();
        SCHED0();
        __builtin_amdgcn_s_setprio(1);
#pragma unroll
        for (int m = 0; m < 8; ++m) {
            acc[m][2] = __builtin_amdgcn_mfma_f32_16x16x32_bf16(
                __builtin_bit_cast(bf16x8, af[m]), __builtin_bit_cast(bf16x8, bfr[2]), acc[m][2], 0, 0, 0);
            acc[m][3] = __builtin_amdgcn_mfma_f32_16x16x32_bf16(
                __builtin_bit_cast(bf16x8, af[m]), __builtin_bit_cast(bf16x8, bfr[3]), acc[m][3], 0, 0, 0);
        }
        __builtin_amdgcn_s_setprio(0);
        SCHED0();
        __builtin_amdgcn_s_barrier();
        SCHED0();

        s_cur += 1; if (s_cur >= 4) s_cur = 0;
    }
    asm volatile("s_waitcnt vmcnt(0)" ::: "memory");   // drain before LDS dealloc
    SCHED0();

    // epilogue
#pragma unroll
    for (int mf = 0; mf < 8; ++mf) {
        const int grow0 = m0 + wm * 128 + mf * 16 + g * 4;
        float rs[4] = {0.f, 0.f, 0.f, 0.f};
        float invl[4];
        if constexpr (EPI == 2) {
#pragma unroll
            for (int r = 0; r < 4; ++r) invl[r] = 1.0f / lz[grow0 + r];
        }
#pragma unroll
        for (int nf = 0; nf < 4; ++nf) {
            const int gcol = n0 + wn * 64 + nf * 16 + r16;
            float bcol = (BIAS_MODE == 1) ? bias[gcol] : 0.f;
#pragma unroll
            for (int r = 0; r < 4; ++r) {
                float v = acc[mf][nf][r];
                float bb = (BIAS_MODE == 1) ? bcol : ((BIAS_MODE == 2) ? bias[grow0 + r] : 0.f);
                v = (v + bb) * scale;
                if constexpr (EPI == 0) {
                    if constexpr (sizeof(TO) == 2)
                        ((uint16_t*)D)[(size_t)(grow0 + r) * ldd + gcol] = f2bf(v);
                    else
                        ((float*)D)[(size_t)(grow0 + r) * ldd + gcol] = v;
                } else if constexpr (EPI == 1) {
                    float e = __expf(v);
                    uint16_t h = f2bf(e);
                    ((uint16_t*)D)[(size_t)(grow0 + r) * ldd + gcol] = h;
                    rs[r] += bf2f(h);          // sum the ROUNDED value for consistency
                } else {
                    ((float*)D)[(size_t)(grow0 + r) * ldd + gcol] = v * invl[r];
                }
            }
        }
        if constexpr (EPI == 1) {
#pragma unroll
            for (int r = 0; r < 4; ++r) {
                float s = rs[r];
                s += __shfl_xor(s, 1);
                s += __shfl_xor(s, 2);
                s += __shfl_xor(s, 4);
                s += __shfl_xor(s, 8);
                if ((lane & 15) == 0) atomicAdd(&lz[grow0 + r], s);
            }
        }
    }
}

extern "C" void kernel_launch(void* const* d_in, const int* in_sizes, int n_in,
                              void* d_out, int out_size, void* d_ws, size_t ws_size,
                              hipStream_t stream)
{
    const float* q_in = (const float*)d_in[0];
    const float* k_in = (const float*)d_in[1];
    const float* v_in = (const float*)d_in[2];
    const float* Wq   = (const float*)d_in[3];
    const float* bq   = (const float*)d_in[4];
    const float* Wk   = (const float*)d_in[5];
    const float* bk   = (const float*)d_in[6];
    const float* Wv   = (const float*)d_in[7];
    const float* bv   = (const float*)d_in[8];

    const size_t MS = (size_t)16384 * 1024;      // 16M elems (32 MB bf16)
    const size_t WS = (size_t)1024 * 1024;       // weight elems
    const size_t SS = (size_t)8 * 2048 * 2048;   // scores elems
    size_t needed = (3 * MS + SS) * sizeof(uint16_t) + 16384 * sizeof(float);
    if (ws_size < needed) return;

    uint16_t* Qb = (uint16_t*)d_ws;      // [16384][1024] bf16, pre-scaled 1/32
    uint16_t* Kb = Qb + MS;              // [16384][1024]
    uint16_t* VT = Kb + MS;              // [8][1024][2048] (V^T per batch)
    uint16_t* Sc = VT + MS;              // [8][2048][2048] E = exp(scores)
    float*    lrow = (float*)(Sc + SS);  // [8][2048] row sums of E

    // temporaries that die before their region is overwritten:
    uint16_t* Xv  = Sc;                  // dead after V-proj (scores written later)
    uint16_t* Wqb = Sc + MS;
    uint16_t* Wkb = Wqb + WS;
    uint16_t* Wvb = Wkb + WS;
    uint16_t* Xq  = (uint16_t*)d_out;    // d_out holds Xq+Xk bf16; PV overwrites at end
    uint16_t* Xk  = Xq + MS;

    dim3 blk(256);
    dim3 blk5(512);

    zero_f32<<<dim3(64), blk, 0, stream>>>(lrow, 16384);

    cvt3_f32_bf16<<<dim3(1024, 3), blk, 0, stream>>>(
        q_in, k_in, v_in, Xq, Xk, Xv, (int)(MS / 8));
    cvt3_f32_bf16<<<dim3(128, 3), blk, 0, stream>>>(
        Wq, Wk, Wv, Wqb, Wkb, Wvb, (int)(WS / 8));

    // Q = (Xq Wq^T + bq)/32 : M=16384 N=1024 K=1024 -> grid 64x4
    gemm256<uint16_t, 1, 0><<<dim3(256, 1), blk5, 0, stream>>>(
        Xq, Wqb, bq, nullptr, Qb, 1024, 1024, 1024, 1024, 4, 0, 0, 0, 0.03125f);
    // K = Xk Wk^T + bk
    gemm256<uint16_t, 1, 0><<<dim3(256, 1), blk5, 0, stream>>>(
        Xk, Wkb, bk, nullptr, Kb, 1024, 1024, 1024, 1024, 4, 0, 0, 0, 1.0f);
    // V^T[b][f][s] = Wv[f][:] . Xv[b][s][:] + bv[f] : M=1024 N=2048 K=1024 -> 4x8 per batch
    gemm256<uint16_t, 2, 0><<<dim3(32, 8), blk5, 0, stream>>>(
        Wvb, Xv, bv, nullptr, VT, 1024, 1024, 2048, 1024, 8,
        0, (long long)2048 * 1024, (long long)1024 * 2048, 1.0f);
    // E[b][q][k] = exp(Qb[b][q][:] . Kb[b][k][:]) ; lrow[b][q] += row sums
    gemm256<uint16_t, 0, 1><<<dim3(64, 8), blk5, 0, stream>>>(
        Qb, Kb, nullptr, lrow, Sc, 1024, 1024, 2048, 1024, 8,
        (long long)2048 * 1024, (long long)2048 * 1024, (long long)2048 * 2048, 1.0f);
    // out[b][q][e] = (E[b][q][:] . VT[b][e][:]) / lrow[b][q] : M=2048 N=1024 K=2048
    gemm256<float, 0, 2><<<dim3(32, 8), blk5, 0, stream>>>(
        Sc, VT, nullptr, lrow, (float*)d_out, 2048, 2048, 1024, 2048, 4,
        (long long)2048 * 2048, (long long)1024 * 2048, (long long)2048 * 1024, 1.0f);
}